// Round 13
// baseline (1243.489 us; speedup 1.0000x reference)
//
#include <hip/hip_runtime.h>
#include <cstdint>
#include <math.h>

#define B       64
#define DF      172
#define HDIM    256
#define KSAMP   16
#define THREADS 512

typedef const __attribute__((address_space(1))) unsigned int* gp_t;
typedef __attribute__((address_space(3))) unsigned int* lp_t;

// NOTE: macro params must not collide with float4 member accessors (.x/.y/.z/.w)
#define FMA4(A_, S_, W_) \
  A_.x = fmaf(S_, W_.x, A_.x); A_.y = fmaf(S_, W_.y, A_.y); \
  A_.z = fmaf(S_, W_.z, A_.z); A_.w = fmaf(S_, W_.w, A_.w);

// ---------------- threefry2x32 (bit-exact vs JAX, partitionable scheme) ----------------
__device__ __forceinline__ uint32_t rotl32(uint32_t x, int d) {
  return (x << d) | (x >> (32 - d));
}

__device__ __forceinline__ void threefry2x32(uint32_t k0, uint32_t k1,
                                             uint32_t& x0, uint32_t& x1) {
  const uint32_t ks0 = k0, ks1 = k1, ks2 = k0 ^ k1 ^ 0x1BD11BDAu;
  x0 += ks0; x1 += ks1;
#define TF_R4(ra,rb,rc,rd) \
  x0 += x1; x1 = rotl32(x1, ra); x1 ^= x0; \
  x0 += x1; x1 = rotl32(x1, rb); x1 ^= x0; \
  x0 += x1; x1 = rotl32(x1, rc); x1 ^= x0; \
  x0 += x1; x1 = rotl32(x1, rd); x1 ^= x0;
  TF_R4(13,15,26,6)  x0 += ks1; x1 += ks2 + 1u;
  TF_R4(17,29,16,24) x0 += ks2; x1 += ks0 + 2u;
  TF_R4(13,15,26,6)  x0 += ks0; x1 += ks1 + 3u;
  TF_R4(17,29,16,24) x0 += ks1; x1 += ks2 + 4u;
  TF_R4(13,15,26,6)  x0 += ks2; x1 += ks0 + 5u;
#undef TF_R4
}

// ---------------- async stage 44032 B (2752 float4) global -> LDS ----------------
__device__ __forceinline__ void stage_async(const float* __restrict__ g,
                                            float* l, int t) {
#pragma unroll
  for (int it = 0; it < 5; ++it) {
    const int i  = it * 512 + t;
    const int ib = it * 512 + (t & ~63);   // wave-uniform LDS base
    __builtin_amdgcn_global_load_lds((gp_t)(g + i * 4), (lp_t)(l + ib * 4), 16, 0, 0);
  }
  if (t < 192) {                           // tail: 3 full waves
    const int i  = 2560 + t;
    const int ib = 2560 + (t & ~63);
    __builtin_amdgcn_global_load_lds((gp_t)(g + i * 4), (lp_t)(l + ib * 4), 16, 0, 0);
  }
}

// ---------------- encode GEMM: [64 x 172] @ [172 x 64] + bias, relu ----------------
// 12-float4 W ring, prefetch distance 8 k (~128 solo cyc; ~512 with 4-wave interleave).
// Legal under VGPR cap 128 (bounds(,2)); spilled at cap 64 in round 8.
// thread (b2 = t>>4: rows 2*b2, 2*b2+1; cg = t&15: cols 4cg..4cg+3); k strictly 0..171.
#define ENC_STEP(W0_, W1_, W2_, W3_, KK_) { \
  const float4 x0 = A0[(KK_) >> 2]; \
  const float4 x1 = A1[(KK_) >> 2]; \
  FMA4(acc0, x0.x, W0_) FMA4(acc0, x0.y, W1_) FMA4(acc0, x0.z, W2_) FMA4(acc0, x0.w, W3_) \
  FMA4(acc1, x1.x, W0_) FMA4(acc1, x1.y, W1_) FMA4(acc1, x1.z, W2_) FMA4(acc1, x1.w, W3_) }

#define ENC_LOAD(W0_, W1_, W2_, W3_, KK_) { \
  W0_ = W4[(KK_) * 16 + cg]; W1_ = W4[((KK_) + 1) * 16 + cg]; \
  W2_ = W4[((KK_) + 2) * 16 + cg]; W3_ = W4[((KK_) + 3) * 16 + cg]; }

__device__ __forceinline__ void enc_gemm_ring(const float* __restrict__ stage,
                                              const float* __restrict__ W,
                                              const float* __restrict__ bias,
                                              float* __restrict__ out,
                                              int b2, int cg) {
  const float4* W4 = (const float4*)W;                       // [172][16]
  const float4* A0 = (const float4*)(stage + (2 * b2) * DF);
  const float4* A1 = (const float4*)(stage + (2 * b2 + 1) * DF);
  float4 acc0 = ((const float4*)bias)[cg];
  float4 acc1 = acc0;
  float4 a0, a1, a2, a3, b0, b1, b2_, b3, c0, c1, c2, c3;
  ENC_LOAD(a0, a1, a2, a3, 0)
  ENC_LOAD(b0, b1, b2_, b3, 4)
  ENC_LOAD(c0, c1, c2, c3, 8)
  for (int k0 = 0; k0 < 156; k0 += 12) {     // k0 = 0,12,...,144
    ENC_STEP(a0, a1, a2, a3, k0)       ENC_LOAD(a0, a1, a2, a3, k0 + 12)
    ENC_STEP(b0, b1, b2_, b3, k0 + 4)  ENC_LOAD(b0, b1, b2_, b3, k0 + 16)
    ENC_STEP(c0, c1, c2, c3, k0 + 8)   ENC_LOAD(c0, c1, c2, c3, k0 + 20)
  }
  ENC_STEP(a0, a1, a2, a3, 156)
  ENC_STEP(b0, b1, b2_, b3, 160)
  ENC_STEP(c0, c1, c2, c3, 164)
  ENC_LOAD(a0, a1, a2, a3, 168)
  ENC_STEP(a0, a1, a2, a3, 168)
  float4 o0 = make_float4(fmaxf(acc0.x, 0.f), fmaxf(acc0.y, 0.f), fmaxf(acc0.z, 0.f), fmaxf(acc0.w, 0.f));
  float4 o1 = make_float4(fmaxf(acc1.x, 0.f), fmaxf(acc1.y, 0.f), fmaxf(acc1.z, 0.f), fmaxf(acc1.w, 0.f));
  ((float4*)out)[(2 * b2) * 16 + cg]     = o0;
  ((float4*)out)[(2 * b2 + 1) * 16 + cg] = o1;
}

// ---------------- h_link piece: acc[16 rows][2 h] += enc @ Wl[off:off+64, 2c2..2c2+1]
// 2-step W prefetch (groups A/B, 8 float2 in flight = 512-cyc cover). Named regs only
// (rule 20). d ascends strictly 0..63 -> accumulation order identical to prior rounds.
#define ACC16_STEP(WA_, WB_, WC_, WD_, DD_) { \
  _Pragma("unroll") \
  for (int i = 0; i < 16; ++i) { \
    const float4 e = *(const float4*)&enc[(r16 + i) * 64 + (DD_)]; \
    acc[i].x = fmaf(e.x, WA_.x, acc[i].x); acc[i].y = fmaf(e.x, WA_.y, acc[i].y); \
    acc[i].x = fmaf(e.y, WB_.x, acc[i].x); acc[i].y = fmaf(e.y, WB_.y, acc[i].y); \
    acc[i].x = fmaf(e.z, WC_.x, acc[i].x); acc[i].y = fmaf(e.z, WC_.y, acc[i].y); \
    acc[i].x = fmaf(e.w, WD_.x, acc[i].x); acc[i].y = fmaf(e.w, WD_.y, acc[i].y); \
  } }

__device__ __forceinline__ void accum16(float2 (&acc)[16],
                                        const float* __restrict__ enc, int r16,
                                        const float2* __restrict__ Wlp) {
  float2 a0 = Wlp[0 * 128],       a1 = Wlp[1 * 128],       a2 = Wlp[2 * 128],       a3 = Wlp[3 * 128];
  float2 b0 = Wlp[4 * 128],       b1 = Wlp[5 * 128],       b2 = Wlp[6 * 128],       b3 = Wlp[7 * 128];
  for (int d0 = 0; d0 < 64; d0 += 8) {
    {  // step A: d = d0..d0+3
      const float2 wa = a0, wb = a1, wc = a2, wd = a3;
      if (d0 < 56) {
        const float2* p = Wlp + (d0 + 8) * 128;
        a0 = p[0]; a1 = p[128]; a2 = p[256]; a3 = p[384];
      }
      ACC16_STEP(wa, wb, wc, wd, d0)
    }
    {  // step B: d = d0+4..d0+7
      const float2 wa = b0, wb = b1, wc = b2, wd = b3;
      if (d0 < 56) {
        const float2* p = Wlp + (d0 + 12) * 128;
        b0 = p[0]; b1 = p[128]; b2 = p[256]; b3 = p[384];
      }
      ACC16_STEP(wa, wb, wc, wd, d0 + 4)
    }
  }
}

// bounds(512,2): VGPR cap 128. VGPR<=128 => 4 waves/SIMD (16/CU) — the SAME occupancy
// the 80.9KB LDS allows (2 blocks/CU), so the deeper prefetch costs nothing.
__global__ __launch_bounds__(THREADS, 2)
void AdaptSampler_kernel(const float* __restrict__ rootf,   // [n,172]
                         const float* __restrict__ root_ts, // [n]
                         const float* __restrict__ nf,      // [n,64,172]
                         const float* __restrict__ ef,      // [n,64,172]
                         const float* __restrict__ nts,     // [n,64]
                         const int*   __restrict__ nid,     // [n,64]
                         const float* __restrict__ Wn,      // [172,64]
                         const float* __restrict__ bn,      // [64]
                         const float* __restrict__ We,      // [172,64]
                         const float* __restrict__ be,      // [64]
                         const float* __restrict__ Wl,      // [320,256]
                         const float* __restrict__ Wr,      // [192,256]
                         float* __restrict__ out_probs,     // [n,64]
                         float* __restrict__ out_action)    // [n,16] (as float)
{
  __shared__ float nf_stage[B * DF];    // 44032 B: nf -> ef -> freq_enc (first 16 KB)
  __shared__ float encA[B * 64];        // 16384 B: node_enc -> edge_enc
  __shared__ float encB[B * 64];        // 16384 B: time_enc
  __shared__ float hroot_lds[HDIM];
  __shared__ float rootenc_lds[192];
  __shared__ float w_lds[B];
  __shared__ float ts_lds[B];
  __shared__ __align__(16) int nid_lds[B];
  __shared__ float freq_lds[B];
  __shared__ unsigned long long mask_lds[B];  // 512 B: per-row equality bitmask
  __shared__ float scpart[4][16][2];          // 512 B: score partials (2 col-halves)
  // total 80896 B -> 2 blocks/CU

  const int n = blockIdx.x;
  const int t = threadIdx.x;
  const int c2  = t & 127;        // accum col-pair (2 h)
  const int r16 = (t >> 7) * 16;  // accum row base (16 rows)
  const int b2 = t >> 4;          // enc row-pair
  const int cg = t & 15;          // enc col-group
  const float2* Wl2 = (const float2*)Wl;  // [320][128] float2

  // ---------------- P0: stage nf; wave 7: basis/nid/ts + root_feat + masks/freq ----------------
  stage_async(nf + (size_t)n * B * DF, nf_stage, t);
  if (t >= 448) {
    const int j = t - 448;
    double e = 9.0 * (double)j / 63.0;   // np.linspace in f64
    const float wj = (float)(1.0 / pow(10.0, e));
    w_lds[j]   = wj;
    nid_lds[j] = nid[n * B + j];
    ts_lds[j]  = nts[n * B + j];
    float a = bn[j];
    const float* rr = rootf + (size_t)n * DF;
#pragma unroll 4
    for (int d = 0; d < DF; ++d) a = fmaf(rr[d], Wn[d * 64 + j], a);
    rootenc_lds[j]       = fmaxf(a, 0.0f);
    rootenc_lds[64 + j]  = 1.0f;         // cos(0*w)
    rootenc_lds[128 + j] = cosf(wj);     // cos(1*w)
    // equality masks + freq (intra-wave LDS RAW on nid_lds: hw-ordered via lgkmcnt)
    const int my = nid_lds[j];
    unsigned long long m = 0ull;
    for (int k = 0; k < B; ++k)
      m |= ((unsigned long long)(nid_lds[k] == my)) << k;
    mask_lds[j] = m;
    freq_lds[j] = (float)__popcll(m) * 0.015625f;
  }
  __syncthreads();

  // ---------------- P1: node_enc -> encA (ring); time_enc -> encB; h_root ----------------
  enc_gemm_ring(nf_stage, Wn, bn, encA, b2, cg);
  {
    const float rts = root_ts[n];
#pragma unroll
    for (int q = 0; q < 8; ++q) {
      const int idx = q * 512 + t;       // stride-1 across lanes: conflict-free
      const int bb = idx >> 6, dd = idx & 63;
      encB[idx] = cosf((rts - ts_lds[bb]) * w_lds[dd]);
    }
  }
  {
    const int h = t >> 1, hf = t & 1;
    float a = 0.0f;
    for (int d = hf * 96; d < hf * 96 + 96; ++d)
      a = fmaf(rootenc_lds[d], Wr[d * HDIM + h], a);
    a += __shfl_xor(a, 1);
    if (hf == 0) hroot_lds[h] = fmaxf(a, 0.0f);
  }
  __syncthreads();

  // ---------------- P2: issue ef stage; accum node (d 0..63) ----------------
  stage_async(ef + (size_t)n * B * DF, nf_stage, t);
  float2 acc[16];
#pragma unroll
  for (int i = 0; i < 16; ++i) acc[i] = make_float2(0.f, 0.f);
  accum16(acc, encA, r16, Wl2 + c2);
  __syncthreads();

  // ---------------- P3: edge_enc -> encA (ring; legal under cap 128) ----------------
  enc_gemm_ring(nf_stage, We, be, encA, b2, cg);
  __syncthreads();

  // ---------------- P4: freq_enc -> nf_stage (free after P3); accum edge (d 64..127) ----------------
#pragma unroll
  for (int q = 0; q < 8; ++q) {
    const int idx = q * 512 + t;
    const int bb = idx >> 6, dd = idx & 63;
    nf_stage[idx] = cosf(freq_lds[bb] * w_lds[dd]);
  }
  accum16(acc, encA, r16, Wl2 + 64 * 128 + c2);
  __syncthreads();

  // ---------------- P6: accum time (128..191), freq (192..255), iden sparse (256..319) ----------------
  accum16(acc, encB, r16, Wl2 + 128 * 128 + c2);
  accum16(acc, nf_stage, r16, Wl2 + 192 * 128 + c2);
  {
    // iden[r][d] = (nid[d]==nid[r]); fmaf(0,w,acc)==acc exactly, so only set bits
    // contribute; ascending-d ctz iteration keeps bit-identical accumulation order.
    // FULLY unrolled so acc[i] index is compile-time (rule #20).
    const float2* Wlp = Wl2 + 256 * 128 + c2;
#pragma unroll
    for (int i = 0; i < 16; ++i) {
      unsigned long long m = mask_lds[r16 + i];   // wave-uniform -> no divergence
      while (m) {
        const int d = __builtin_ctzll(m);
        m &= m - 1;
        const float2 wv = Wlp[d * 128];
        acc[i].x += wv.x;  // == fmaf(1.0f, wv.x, acc)
        acc[i].y += wv.y;
      }
    }
  }

  // ---------------- scores: relu(h_link) . h_root; butterfly 64 + 2 LDS partials ----------------
  {
    const float2 hr = ((const float2*)hroot_lds)[c2];
#pragma unroll
    for (int i = 0; i < 16; ++i) {
      float s = fmaxf(acc[i].x, 0.f) * hr.x;
      s = fmaf(fmaxf(acc[i].y, 0.f), hr.y, s);
#pragma unroll
      for (int mm = 32; mm >= 1; mm >>= 1) s += __shfl_xor(s, mm);
      if ((t & 63) == 0) scpart[t >> 7][i][(t >> 6) & 1] = s;
    }
  }
  __syncthreads();

  // ---------------- P7: softmax + gumbel + top-16 (wave 0) ----------------
  if (t < B) {
    float s = (scpart[t >> 4][t & 15][0] + scpart[t >> 4][t & 15][1]) * 0.0625f;
    float m = s;
#pragma unroll
    for (int mm = 32; mm >= 1; mm >>= 1) m = fmaxf(m, __shfl_xor(m, mm));
    float e = expf(s - m);
    float sum = e;
#pragma unroll
    for (int mm = 32; mm >= 1; mm >>= 1) sum += __shfl_xor(sum, mm);
    float p = e / sum;
    out_probs[(size_t)n * B + t] = p;

    // partitionable threefry: block input (0, i), draw = out0 ^ out1
    uint32_t i = (uint32_t)(n * B + t);
    uint32_t x0 = 0u, x1 = i;
    threefry2x32(0u, 42u, x0, x1);
    uint32_t bits = x0 ^ x1;
    float f = __uint_as_float((bits >> 9) | 0x3f800000u) - 1.0f;
    const float TINY = 1.1754943508222875e-38f;
    float u = fmaxf(f * (1.0f - TINY) + TINY, TINY);
    float g = -logf(-logf(u));
    float keyv = logf(p + 1e-20f) + g;

    float v = keyv;
    for (int k = 0; k < KSAMP; ++k) {
      float bv = v; int bi = t;
#pragma unroll
      for (int mm = 32; mm >= 1; mm >>= 1) {
        float ov = __shfl_xor(bv, mm);
        int   oi = __shfl_xor(bi, mm);
        if (ov > bv || (ov == bv && oi < bi)) { bv = ov; bi = oi; }
      }
      if (t == 0) out_action[(size_t)n * KSAMP + k] = (float)bi;
      if (t == bi) v = -3.402823466e+38f;
    }
  }
}

extern "C" void kernel_launch(void* const* d_in, const int* in_sizes, int n_in,
                              void* d_out, int out_size, void* d_ws, size_t ws_size,
                              hipStream_t stream) {
  const float* rootf = (const float*)d_in[0];
  const float* rts   = (const float*)d_in[1];
  const float* nf    = (const float*)d_in[2];
  const float* ef    = (const float*)d_in[3];
  const float* nts   = (const float*)d_in[4];
  const int*   nid   = (const int*)d_in[5];
  const float* Wn    = (const float*)d_in[6];
  const float* bn    = (const float*)d_in[7];
  const float* We    = (const float*)d_in[8];
  const float* be    = (const float*)d_in[9];
  const float* Wl    = (const float*)d_in[10];
  const float* Wr    = (const float*)d_in[11];

  const int n = in_sizes[1];                   // 4096 rows
  float* probs  = (float*)d_out;               // [n,64] f32
  float* action = probs + (size_t)n * B;       // [n,16] written as f32 values

  AdaptSampler_kernel<<<dim3(n), dim3(THREADS), 0, stream>>>(
      rootf, rts, nf, ef, nts, nid, Wn, bn, We, be, Wl, Wr, probs, action);
}

// Round 14
// 1240.105 us; speedup vs baseline: 1.0027x; 1.0027x over previous
//
#include <hip/hip_runtime.h>
#include <cstdint>
#include <math.h>

#define B       64
#define DF      172
#define HDIM    256
#define KSAMP   16
#define THREADS 512

typedef const __attribute__((address_space(1))) unsigned int* gp_t;
typedef __attribute__((address_space(3))) unsigned int* lp_t;

// NOTE: macro params must not collide with float4 member accessors (.x/.y/.z/.w)
#define FMA4(A_, S_, W_) \
  A_.x = fmaf(S_, W_.x, A_.x); A_.y = fmaf(S_, W_.y, A_.y); \
  A_.z = fmaf(S_, W_.z, A_.z); A_.w = fmaf(S_, W_.w, A_.w);

// ---------------- threefry2x32 (bit-exact vs JAX, partitionable scheme) ----------------
__device__ __forceinline__ uint32_t rotl32(uint32_t x, int d) {
  return (x << d) | (x >> (32 - d));
}

__device__ __forceinline__ void threefry2x32(uint32_t k0, uint32_t k1,
                                             uint32_t& x0, uint32_t& x1) {
  const uint32_t ks0 = k0, ks1 = k1, ks2 = k0 ^ k1 ^ 0x1BD11BDAu;
  x0 += ks0; x1 += ks1;
#define TF_R4(ra,rb,rc,rd) \
  x0 += x1; x1 = rotl32(x1, ra); x1 ^= x0; \
  x0 += x1; x1 = rotl32(x1, rb); x1 ^= x0; \
  x0 += x1; x1 = rotl32(x1, rc); x1 ^= x0; \
  x0 += x1; x1 = rotl32(x1, rd); x1 ^= x0;
  TF_R4(13,15,26,6)  x0 += ks1; x1 += ks2 + 1u;
  TF_R4(17,29,16,24) x0 += ks2; x1 += ks0 + 2u;
  TF_R4(13,15,26,6)  x0 += ks0; x1 += ks1 + 3u;
  TF_R4(17,29,16,24) x0 += ks1; x1 += ks2 + 4u;
  TF_R4(13,15,26,6)  x0 += ks2; x1 += ks0 + 5u;
#undef TF_R4
}

// ---------------- async stage 44032 B (2752 float4) global -> LDS ----------------
__device__ __forceinline__ void stage_async(const float* __restrict__ g,
                                            float* l, int t) {
#pragma unroll
  for (int it = 0; it < 5; ++it) {
    const int i  = it * 512 + t;
    const int ib = it * 512 + (t & ~63);   // wave-uniform LDS base
    __builtin_amdgcn_global_load_lds((gp_t)(g + i * 4), (lp_t)(l + ib * 4), 16, 0, 0);
  }
  if (t < 192) {                           // tail: 3 full waves
    const int i  = 2560 + t;
    const int ib = 2560 + (t & ~63);
    __builtin_amdgcn_global_load_lds((gp_t)(g + i * 4), (lp_t)(l + ib * 4), 16, 0, 0);
  }
}

// ---------------- encode GEMM: [64 x 172] @ [172 x 64] + bias, relu ----------------
// 12-float4 W ring, prefetch distance 8 k. Needs VGPR > 64 — legal now that no
// launch_bounds caps the budget (r13 showed natural demand ~80, no spill).
// thread (b2 = t>>4: rows 2*b2, 2*b2+1; cg = t&15: cols 4cg..4cg+3); k strictly 0..171.
#define ENC_STEP(W0_, W1_, W2_, W3_, KK_) { \
  const float4 x0 = A0[(KK_) >> 2]; \
  const float4 x1 = A1[(KK_) >> 2]; \
  FMA4(acc0, x0.x, W0_) FMA4(acc0, x0.y, W1_) FMA4(acc0, x0.z, W2_) FMA4(acc0, x0.w, W3_) \
  FMA4(acc1, x1.x, W0_) FMA4(acc1, x1.y, W1_) FMA4(acc1, x1.z, W2_) FMA4(acc1, x1.w, W3_) }

#define ENC_LOAD(W0_, W1_, W2_, W3_, KK_) { \
  W0_ = W4[(KK_) * 16 + cg]; W1_ = W4[((KK_) + 1) * 16 + cg]; \
  W2_ = W4[((KK_) + 2) * 16 + cg]; W3_ = W4[((KK_) + 3) * 16 + cg]; }

__device__ __forceinline__ void enc_gemm_ring(const float* __restrict__ stage,
                                              const float* __restrict__ W,
                                              const float* __restrict__ bias,
                                              float* __restrict__ out,
                                              int b2, int cg) {
  const float4* W4 = (const float4*)W;                       // [172][16]
  const float4* A0 = (const float4*)(stage + (2 * b2) * DF);
  const float4* A1 = (const float4*)(stage + (2 * b2 + 1) * DF);
  float4 acc0 = ((const float4*)bias)[cg];
  float4 acc1 = acc0;
  float4 a0, a1, a2, a3, b0, b1, b2_, b3, c0, c1, c2, c3;
  ENC_LOAD(a0, a1, a2, a3, 0)
  ENC_LOAD(b0, b1, b2_, b3, 4)
  ENC_LOAD(c0, c1, c2, c3, 8)
  for (int k0 = 0; k0 < 156; k0 += 12) {     // k0 = 0,12,...,144
    ENC_STEP(a0, a1, a2, a3, k0)       ENC_LOAD(a0, a1, a2, a3, k0 + 12)
    ENC_STEP(b0, b1, b2_, b3, k0 + 4)  ENC_LOAD(b0, b1, b2_, b3, k0 + 16)
    ENC_STEP(c0, c1, c2, c3, k0 + 8)   ENC_LOAD(c0, c1, c2, c3, k0 + 20)
  }
  ENC_STEP(a0, a1, a2, a3, 156)
  ENC_STEP(b0, b1, b2_, b3, 160)
  ENC_STEP(c0, c1, c2, c3, 164)
  ENC_LOAD(a0, a1, a2, a3, 168)
  ENC_STEP(a0, a1, a2, a3, 168)
  float4 o0 = make_float4(fmaxf(acc0.x, 0.f), fmaxf(acc0.y, 0.f), fmaxf(acc0.z, 0.f), fmaxf(acc0.w, 0.f));
  float4 o1 = make_float4(fmaxf(acc1.x, 0.f), fmaxf(acc1.y, 0.f), fmaxf(acc1.z, 0.f), fmaxf(acc1.w, 0.f));
  ((float4*)out)[(2 * b2) * 16 + cg]     = o0;
  ((float4*)out)[(2 * b2 + 1) * 16 + cg] = o1;
}

// ---------------- h_link piece: acc[16 rows][2 h] += enc @ Wl[off:off+64, 2c2..2c2+1]
// 2-step W prefetch (groups A/B, 8 float2 in flight). Named regs only (rule 20).
// d ascends strictly 0..63 -> accumulation order identical to prior rounds.
#define ACC16_STEP(WA_, WB_, WC_, WD_, DD_) { \
  _Pragma("unroll") \
  for (int i = 0; i < 16; ++i) { \
    const float4 e = *(const float4*)&enc[(r16 + i) * 64 + (DD_)]; \
    acc[i].x = fmaf(e.x, WA_.x, acc[i].x); acc[i].y = fmaf(e.x, WA_.y, acc[i].y); \
    acc[i].x = fmaf(e.y, WB_.x, acc[i].x); acc[i].y = fmaf(e.y, WB_.y, acc[i].y); \
    acc[i].x = fmaf(e.z, WC_.x, acc[i].x); acc[i].y = fmaf(e.z, WC_.y, acc[i].y); \
    acc[i].x = fmaf(e.w, WD_.x, acc[i].x); acc[i].y = fmaf(e.w, WD_.y, acc[i].y); \
  } }

__device__ __forceinline__ void accum16(float2 (&acc)[16],
                                        const float* __restrict__ enc, int r16,
                                        const float2* __restrict__ Wlp) {
  float2 a0 = Wlp[0 * 128],       a1 = Wlp[1 * 128],       a2 = Wlp[2 * 128],       a3 = Wlp[3 * 128];
  float2 b0 = Wlp[4 * 128],       b1 = Wlp[5 * 128],       b2 = Wlp[6 * 128],       b3 = Wlp[7 * 128];
  for (int d0 = 0; d0 < 64; d0 += 8) {
    {  // step A: d = d0..d0+3
      const float2 wa = a0, wb = a1, wc = a2, wd = a3;
      if (d0 < 56) {
        const float2* p = Wlp + (d0 + 8) * 128;
        a0 = p[0]; a1 = p[128]; a2 = p[256]; a3 = p[384];
      }
      ACC16_STEP(wa, wb, wc, wd, d0)
    }
    {  // step B: d = d0+4..d0+7
      const float2 wa = b0, wb = b1, wc = b2, wd = b3;
      if (d0 < 56) {
        const float2* p = Wlp + (d0 + 12) * 128;
        b0 = p[0]; b1 = p[128]; b2 = p[256]; b3 = p[384];
      }
      ACC16_STEP(wa, wb, wc, wd, d0 + 4)
    }
  }
}

// NO launch_bounds: hipcc's (512,N) sets BOTH a VGPR budget (~256/N) AND an
// occupancy cap (N/2 blocks of 512). Demand here is ~80 VGPR -> HW allows 4+
// waves/SIMD; occupancy then comes from LDS: 80.9KB -> 2 blocks/CU.
__global__
void AdaptSampler_kernel(const float* __restrict__ rootf,   // [n,172]
                         const float* __restrict__ root_ts, // [n]
                         const float* __restrict__ nf,      // [n,64,172]
                         const float* __restrict__ ef,      // [n,64,172]
                         const float* __restrict__ nts,     // [n,64]
                         const int*   __restrict__ nid,     // [n,64]
                         const float* __restrict__ Wn,      // [172,64]
                         const float* __restrict__ bn,      // [64]
                         const float* __restrict__ We,      // [172,64]
                         const float* __restrict__ be,      // [64]
                         const float* __restrict__ Wl,      // [320,256]
                         const float* __restrict__ Wr,      // [192,256]
                         float* __restrict__ out_probs,     // [n,64]
                         float* __restrict__ out_action)    // [n,16] (as float)
{
  __shared__ float nf_stage[B * DF];    // 44032 B: nf -> ef -> freq_enc (first 16 KB)
  __shared__ float encA[B * 64];        // 16384 B: node_enc -> edge_enc
  __shared__ float encB[B * 64];        // 16384 B: time_enc
  __shared__ float hroot_lds[HDIM];
  __shared__ float rootenc_lds[192];
  __shared__ float w_lds[B];
  __shared__ float ts_lds[B];
  __shared__ __align__(16) int nid_lds[B];
  __shared__ float freq_lds[B];
  __shared__ unsigned long long mask_lds[B];  // 512 B: per-row equality bitmask
  __shared__ float scpart[4][16][2];          // 512 B: score partials (2 col-halves)
  // total 80896 B -> 2 blocks/CU

  const int n = blockIdx.x;
  const int t = threadIdx.x;
  const int c2  = t & 127;        // accum col-pair (2 h)
  const int r16 = (t >> 7) * 16;  // accum row base (16 rows)
  const int b2 = t >> 4;          // enc row-pair
  const int cg = t & 15;          // enc col-group
  const float2* Wl2 = (const float2*)Wl;  // [320][128] float2

  // ---------------- P0: stage nf; wave 7: basis/nid/ts + root_feat + masks/freq ----------------
  stage_async(nf + (size_t)n * B * DF, nf_stage, t);
  if (t >= 448) {
    const int j = t - 448;
    double e = 9.0 * (double)j / 63.0;   // np.linspace in f64
    const float wj = (float)(1.0 / pow(10.0, e));
    w_lds[j]   = wj;
    nid_lds[j] = nid[n * B + j];
    ts_lds[j]  = nts[n * B + j];
    float a = bn[j];
    const float* rr = rootf + (size_t)n * DF;
#pragma unroll 4
    for (int d = 0; d < DF; ++d) a = fmaf(rr[d], Wn[d * 64 + j], a);
    rootenc_lds[j]       = fmaxf(a, 0.0f);
    rootenc_lds[64 + j]  = 1.0f;         // cos(0*w)
    rootenc_lds[128 + j] = cosf(wj);     // cos(1*w)
    // equality masks + freq (intra-wave LDS RAW on nid_lds: hw-ordered via lgkmcnt)
    const int my = nid_lds[j];
    unsigned long long m = 0ull;
    for (int k = 0; k < B; ++k)
      m |= ((unsigned long long)(nid_lds[k] == my)) << k;
    mask_lds[j] = m;
    freq_lds[j] = (float)__popcll(m) * 0.015625f;
  }
  __syncthreads();

  // ---------------- P1: node_enc -> encA (ring); time_enc -> encB; h_root ----------------
  enc_gemm_ring(nf_stage, Wn, bn, encA, b2, cg);
  {
    const float rts = root_ts[n];
#pragma unroll
    for (int q = 0; q < 8; ++q) {
      const int idx = q * 512 + t;       // stride-1 across lanes: conflict-free
      const int bb = idx >> 6, dd = idx & 63;
      encB[idx] = cosf((rts - ts_lds[bb]) * w_lds[dd]);
    }
  }
  {
    const int h = t >> 1, hf = t & 1;
    float a = 0.0f;
    for (int d = hf * 96; d < hf * 96 + 96; ++d)
      a = fmaf(rootenc_lds[d], Wr[d * HDIM + h], a);
    a += __shfl_xor(a, 1);
    if (hf == 0) hroot_lds[h] = fmaxf(a, 0.0f);
  }
  __syncthreads();

  // ---------------- P2: issue ef stage; accum node (d 0..63) ----------------
  stage_async(ef + (size_t)n * B * DF, nf_stage, t);
  float2 acc[16];
#pragma unroll
  for (int i = 0; i < 16; ++i) acc[i] = make_float2(0.f, 0.f);
  accum16(acc, encA, r16, Wl2 + c2);
  __syncthreads();

  // ---------------- P3: edge_enc -> encA (ring) ----------------
  enc_gemm_ring(nf_stage, We, be, encA, b2, cg);
  __syncthreads();

  // ---------------- P4: freq_enc -> nf_stage (free after P3); accum edge (d 64..127) ----------------
#pragma unroll
  for (int q = 0; q < 8; ++q) {
    const int idx = q * 512 + t;
    const int bb = idx >> 6, dd = idx & 63;
    nf_stage[idx] = cosf(freq_lds[bb] * w_lds[dd]);
  }
  accum16(acc, encA, r16, Wl2 + 64 * 128 + c2);
  __syncthreads();

  // ---------------- P6: accum time (128..191), freq (192..255), iden sparse (256..319) ----------------
  accum16(acc, encB, r16, Wl2 + 128 * 128 + c2);
  accum16(acc, nf_stage, r16, Wl2 + 192 * 128 + c2);
  {
    // iden[r][d] = (nid[d]==nid[r]); fmaf(0,w,acc)==acc exactly, so only set bits
    // contribute; ascending-d ctz iteration keeps bit-identical accumulation order.
    // FULLY unrolled so acc[i] index is compile-time (rule #20).
    const float2* Wlp = Wl2 + 256 * 128 + c2;
#pragma unroll
    for (int i = 0; i < 16; ++i) {
      unsigned long long m = mask_lds[r16 + i];   // wave-uniform -> no divergence
      while (m) {
        const int d = __builtin_ctzll(m);
        m &= m - 1;
        const float2 wv = Wlp[d * 128];
        acc[i].x += wv.x;  // == fmaf(1.0f, wv.x, acc)
        acc[i].y += wv.y;
      }
    }
  }

  // ---------------- scores: relu(h_link) . h_root; butterfly 64 + 2 LDS partials ----------------
  {
    const float2 hr = ((const float2*)hroot_lds)[c2];
#pragma unroll
    for (int i = 0; i < 16; ++i) {
      float s = fmaxf(acc[i].x, 0.f) * hr.x;
      s = fmaf(fmaxf(acc[i].y, 0.f), hr.y, s);
#pragma unroll
      for (int mm = 32; mm >= 1; mm >>= 1) s += __shfl_xor(s, mm);
      if ((t & 63) == 0) scpart[t >> 7][i][(t >> 6) & 1] = s;
    }
  }
  __syncthreads();

  // ---------------- P7: softmax + gumbel + top-16 (wave 0) ----------------
  if (t < B) {
    float s = (scpart[t >> 4][t & 15][0] + scpart[t >> 4][t & 15][1]) * 0.0625f;
    float m = s;
#pragma unroll
    for (int mm = 32; mm >= 1; mm >>= 1) m = fmaxf(m, __shfl_xor(m, mm));
    float e = expf(s - m);
    float sum = e;
#pragma unroll
    for (int mm = 32; mm >= 1; mm >>= 1) sum += __shfl_xor(sum, mm);
    float p = e / sum;
    out_probs[(size_t)n * B + t] = p;

    // partitionable threefry: block input (0, i), draw = out0 ^ out1
    uint32_t i = (uint32_t)(n * B + t);
    uint32_t x0 = 0u, x1 = i;
    threefry2x32(0u, 42u, x0, x1);
    uint32_t bits = x0 ^ x1;
    float f = __uint_as_float((bits >> 9) | 0x3f800000u) - 1.0f;
    const float TINY = 1.1754943508222875e-38f;
    float u = fmaxf(f * (1.0f - TINY) + TINY, TINY);
    float g = -logf(-logf(u));
    float keyv = logf(p + 1e-20f) + g;

    float v = keyv;
    for (int k = 0; k < KSAMP; ++k) {
      float bv = v; int bi = t;
#pragma unroll
      for (int mm = 32; mm >= 1; mm >>= 1) {
        float ov = __shfl_xor(bv, mm);
        int   oi = __shfl_xor(bi, mm);
        if (ov > bv || (ov == bv && oi < bi)) { bv = ov; bi = oi; }
      }
      if (t == 0) out_action[(size_t)n * KSAMP + k] = (float)bi;
      if (t == bi) v = -3.402823466e+38f;
    }
  }
}

extern "C" void kernel_launch(void* const* d_in, const int* in_sizes, int n_in,
                              void* d_out, int out_size, void* d_ws, size_t ws_size,
                              hipStream_t stream) {
  const float* rootf = (const float*)d_in[0];
  const float* rts   = (const float*)d_in[1];
  const float* nf    = (const float*)d_in[2];
  const float* ef    = (const float*)d_in[3];
  const float* nts   = (const float*)d_in[4];
  const int*   nid   = (const int*)d_in[5];
  const float* Wn    = (const float*)d_in[6];
  const float* bn    = (const float*)d_in[7];
  const float* We    = (const float*)d_in[8];
  const float* be    = (const float*)d_in[9];
  const float* Wl    = (const float*)d_in[10];
  const float* Wr    = (const float*)d_in[11];

  const int n = in_sizes[1];                   // 4096 rows
  float* probs  = (float*)d_out;               // [n,64] f32
  float* action = probs + (size_t)n * B;       // [n,16] written as f32 values

  AdaptSampler_kernel<<<dim3(n), dim3(THREADS), 0, stream>>>(
      rootf, rts, nf, ef, nts, nid, Wn, bn, We, be, Wl, Wr, probs, action);
}

// Round 15
// 876.804 us; speedup vs baseline: 1.4182x; 1.4143x over previous
//
#include <hip/hip_runtime.h>
#include <cstdint>
#include <math.h>

#define B       64
#define DF      172
#define HDIM    256
#define KSAMP   16
#define THREADS 512

typedef const __attribute__((address_space(1))) unsigned int* gp_t;
typedef __attribute__((address_space(3))) unsigned int* lp_t;

// NOTE: macro params must not collide with float4 member accessors (.x/.y/.z/.w)
#define FMA4(A_, S_, W_) \
  A_.x = fmaf(S_, W_.x, A_.x); A_.y = fmaf(S_, W_.y, A_.y); \
  A_.z = fmaf(S_, W_.z, A_.z); A_.w = fmaf(S_, W_.w, A_.w);

// ---------------- threefry2x32 (bit-exact vs JAX, partitionable scheme) ----------------
__device__ __forceinline__ uint32_t rotl32(uint32_t x, int d) {
  return (x << d) | (x >> (32 - d));
}

__device__ __forceinline__ void threefry2x32(uint32_t k0, uint32_t k1,
                                             uint32_t& x0, uint32_t& x1) {
  const uint32_t ks0 = k0, ks1 = k1, ks2 = k0 ^ k1 ^ 0x1BD11BDAu;
  x0 += ks0; x1 += ks1;
#define TF_R4(ra,rb,rc,rd) \
  x0 += x1; x1 = rotl32(x1, ra); x1 ^= x0; \
  x0 += x1; x1 = rotl32(x1, rb); x1 ^= x0; \
  x0 += x1; x1 = rotl32(x1, rc); x1 ^= x0; \
  x0 += x1; x1 = rotl32(x1, rd); x1 ^= x0;
  TF_R4(13,15,26,6)  x0 += ks1; x1 += ks2 + 1u;
  TF_R4(17,29,16,24) x0 += ks2; x1 += ks0 + 2u;
  TF_R4(13,15,26,6)  x0 += ks0; x1 += ks1 + 3u;
  TF_R4(17,29,16,24) x0 += ks1; x1 += ks2 + 4u;
  TF_R4(13,15,26,6)  x0 += ks2; x1 += ks0 + 5u;
#undef TF_R4
}

// ---------------- async stage 44032 B (2752 float4) global -> LDS ----------------
__device__ __forceinline__ void stage_async(const float* __restrict__ g,
                                            float* l, int t) {
#pragma unroll
  for (int it = 0; it < 5; ++it) {
    const int i  = it * 512 + t;
    const int ib = it * 512 + (t & ~63);   // wave-uniform LDS base
    __builtin_amdgcn_global_load_lds((gp_t)(g + i * 4), (lp_t)(l + ib * 4), 16, 0, 0);
  }
  if (t < 192) {                           // tail: 3 full waves
    const int i  = 2560 + t;
    const int ib = 2560 + (t & ~63);
    __builtin_amdgcn_global_load_lds((gp_t)(g + i * 4), (lp_t)(l + ib * 4), 16, 0, 0);
  }
}

// ---------------- encode GEMM: [64 x 172] @ [172 x 64] + bias, relu ----------------
// thread (b2 = t>>4: rows 2*b2, 2*b2+1; cg = t&15: cols 4cg..4cg+3)
// Both variants accumulate k = 0..171 in identical order (bit-identical results).
#define ENC_STEP(W0_, W1_, W2_, W3_, KK_) { \
  const float4 x0 = A0[(KK_) >> 2]; \
  const float4 x1 = A1[(KK_) >> 2]; \
  FMA4(acc0, x0.x, W0_) FMA4(acc0, x0.y, W1_) FMA4(acc0, x0.z, W2_) FMA4(acc0, x0.w, W3_) \
  FMA4(acc1, x1.x, W0_) FMA4(acc1, x1.y, W1_) FMA4(acc1, x1.z, W2_) FMA4(acc1, x1.w, W3_) }

#define ENC_LOAD(W0_, W1_, W2_, W3_, KK_) { \
  W0_ = W4[(KK_) * 16 + cg]; W1_ = W4[((KK_) + 1) * 16 + cg]; \
  W2_ = W4[((KK_) + 2) * 16 + cg]; W3_ = W4[((KK_) + 3) * 16 + cg]; }

// Ring variant: 12 float4 W regs, prefetch distance 8 k. Use ONLY where acc[16] is
// NOT live (P1) — under the 64-VGPR budget (bounds(,4)) it spills in P3 (round 8).
__device__ __forceinline__ void enc_gemm_ring(const float* __restrict__ stage,
                                              const float* __restrict__ W,
                                              const float* __restrict__ bias,
                                              float* __restrict__ out,
                                              int b2, int cg) {
  const float4* W4 = (const float4*)W;                       // [172][16]
  const float4* A0 = (const float4*)(stage + (2 * b2) * DF);
  const float4* A1 = (const float4*)(stage + (2 * b2 + 1) * DF);
  float4 acc0 = ((const float4*)bias)[cg];
  float4 acc1 = acc0;
  float4 a0, a1, a2, a3, b0, b1, b2_, b3, c0, c1, c2, c3;
  ENC_LOAD(a0, a1, a2, a3, 0)
  ENC_LOAD(b0, b1, b2_, b3, 4)
  ENC_LOAD(c0, c1, c2, c3, 8)
  for (int k0 = 0; k0 < 156; k0 += 12) {     // k0 = 0,12,...,144
    ENC_STEP(a0, a1, a2, a3, k0)       ENC_LOAD(a0, a1, a2, a3, k0 + 12)
    ENC_STEP(b0, b1, b2_, b3, k0 + 4)  ENC_LOAD(b0, b1, b2_, b3, k0 + 16)
    ENC_STEP(c0, c1, c2, c3, k0 + 8)   ENC_LOAD(c0, c1, c2, c3, k0 + 20)
  }
  ENC_STEP(a0, a1, a2, a3, 156)  ENC_LOAD(a0, a1, a2, a3, 168)
  ENC_STEP(b0, b1, b2_, b3, 160)
  ENC_STEP(c0, c1, c2, c3, 164)
  ENC_STEP(a0, a1, a2, a3, 168)
  float4 o0 = make_float4(fmaxf(acc0.x, 0.f), fmaxf(acc0.y, 0.f), fmaxf(acc0.z, 0.f), fmaxf(acc0.w, 0.f));
  float4 o1 = make_float4(fmaxf(acc1.x, 0.f), fmaxf(acc1.y, 0.f), fmaxf(acc1.z, 0.f), fmaxf(acc1.w, 0.f));
  ((float4*)out)[(2 * b2) * 16 + cg]     = o0;
  ((float4*)out)[(2 * b2 + 1) * 16 + cg] = o1;
}

// Lite variant: 8 float4 W regs, 1-group prefetch. Used in P3 where acc[16] is live.
__device__ __forceinline__ void enc_gemm_lite(const float* __restrict__ stage,
                                              const float* __restrict__ W,
                                              const float* __restrict__ bias,
                                              float* __restrict__ out,
                                              int b2, int cg) {
  const float4* W4 = (const float4*)W;                       // [172][16]
  const float4* A0 = (const float4*)(stage + (2 * b2) * DF);
  const float4* A1 = (const float4*)(stage + (2 * b2 + 1) * DF);
  float4 acc0 = ((const float4*)bias)[cg];
  float4 acc1 = acc0;
  float4 w0 = W4[0 * 16 + cg], w1 = W4[1 * 16 + cg];
  float4 w2 = W4[2 * 16 + cg], w3 = W4[3 * 16 + cg];
  for (int k = 0; k < DF; k += 4) {
    const float4 wa = w0, wb = w1, wc = w2, wd = w3;
    if (k < DF - 4) {
      w0 = W4[(k + 4) * 16 + cg]; w1 = W4[(k + 5) * 16 + cg];
      w2 = W4[(k + 6) * 16 + cg]; w3 = W4[(k + 7) * 16 + cg];
    }
    ENC_STEP(wa, wb, wc, wd, k)
  }
  float4 o0 = make_float4(fmaxf(acc0.x, 0.f), fmaxf(acc0.y, 0.f), fmaxf(acc0.z, 0.f), fmaxf(acc0.w, 0.f));
  float4 o1 = make_float4(fmaxf(acc1.x, 0.f), fmaxf(acc1.y, 0.f), fmaxf(acc1.z, 0.f), fmaxf(acc1.w, 0.f));
  ((float4*)out)[(2 * b2) * 16 + cg]     = o0;
  ((float4*)out)[(2 * b2 + 1) * 16 + cg] = o1;
}

// ---------------- h_link piece: acc[16 rows][2 h] += enc @ Wl[off:off+64, 2c2..2c2+1]
// Wlp = ((const float2*)Wl) + off*128 + c2 ; row stride 128 float2 (coalesced 512B/wave)
__device__ __forceinline__ void accum16(float2 (&acc)[16],
                                        const float* __restrict__ enc, int r16,
                                        const float2* __restrict__ Wlp) {
  float2 w0 = Wlp[0], w1 = Wlp[128], w2 = Wlp[256], w3 = Wlp[384];
  for (int d0 = 0; d0 < 64; d0 += 4) {
    const float2 wa = w0, wb = w1, wc = w2, wd = w3;
    if (d0 < 60) {
      const float2* p = Wlp + (d0 + 4) * 128;
      w0 = p[0]; w1 = p[128]; w2 = p[256]; w3 = p[384];
    }
#pragma unroll
    for (int i = 0; i < 16; ++i) {
      const float4 e = *(const float4*)&enc[(r16 + i) * 64 + d0];  // wave-uniform broadcast
      acc[i].x = fmaf(e.x, wa.x, acc[i].x); acc[i].y = fmaf(e.x, wa.y, acc[i].y);
      acc[i].x = fmaf(e.y, wb.x, acc[i].x); acc[i].y = fmaf(e.y, wb.y, acc[i].y);
      acc[i].x = fmaf(e.z, wc.x, acc[i].x); acc[i].y = fmaf(e.z, wc.y, acc[i].y);
      acc[i].x = fmaf(e.w, wd.x, acc[i].x); acc[i].y = fmaf(e.w, wd.y, acc[i].y);
    }
  }
}

// bounds(512,4): VGPR budget 64 (hipcc pool model 256/N), occupancy 2 blocks/CU.
// Champion configuration (r9: 880us, VGPR 60, no spills).
__global__ __launch_bounds__(THREADS, 4)
void AdaptSampler_kernel(const float* __restrict__ rootf,   // [n,172]
                         const float* __restrict__ root_ts, // [n]
                         const float* __restrict__ nf,      // [n,64,172]
                         const float* __restrict__ ef,      // [n,64,172]
                         const float* __restrict__ nts,     // [n,64]
                         const int*   __restrict__ nid,     // [n,64]
                         const float* __restrict__ Wn,      // [172,64]
                         const float* __restrict__ bn,      // [64]
                         const float* __restrict__ We,      // [172,64]
                         const float* __restrict__ be,      // [64]
                         const float* __restrict__ Wl,      // [320,256]
                         const float* __restrict__ Wr,      // [192,256]
                         float* __restrict__ out_probs,     // [n,64]
                         float* __restrict__ out_action)    // [n,16] (as float)
{
  __shared__ float nf_stage[B * DF];    // 44032 B: nf -> ef -> freq_enc (first 16 KB)
  __shared__ float encA[B * 64];        // 16384 B: node_enc -> edge_enc
  __shared__ float encB[B * 64];        // 16384 B: time_enc
  __shared__ float hroot_lds[HDIM];
  __shared__ float rootenc_lds[192];
  __shared__ float w_lds[B];
  __shared__ float ts_lds[B];
  __shared__ __align__(16) int nid_lds[B];
  __shared__ float freq_lds[B];
  __shared__ unsigned long long mask_lds[B];  // 512 B: per-row equality bitmask
  __shared__ float scpart[4][16][2];          // 512 B: score partials (2 col-halves)
  // total 80896 B -> 2 blocks/CU

  const int n = blockIdx.x;
  const int t = threadIdx.x;
  const int c2  = t & 127;        // accum col-pair (2 h)
  const int r16 = (t >> 7) * 16;  // accum row base (16 rows)
  const int b2 = t >> 4;          // enc row-pair
  const int cg = t & 15;          // enc col-group
  const float2* Wl2 = (const float2*)Wl;  // [320][128] float2

  // ---------------- P0: stage nf; wave 7: basis/nid/ts + root_feat + masks/freq ----------------
  stage_async(nf + (size_t)n * B * DF, nf_stage, t);
  if (t >= 448) {
    const int j = t - 448;
    double e = 9.0 * (double)j / 63.0;   // np.linspace in f64
    const float wj = (float)(1.0 / pow(10.0, e));
    w_lds[j]   = wj;
    nid_lds[j] = nid[n * B + j];
    ts_lds[j]  = nts[n * B + j];
    float a = bn[j];
    const float* rr = rootf + (size_t)n * DF;
#pragma unroll 4
    for (int d = 0; d < DF; ++d) a = fmaf(rr[d], Wn[d * 64 + j], a);
    rootenc_lds[j]       = fmaxf(a, 0.0f);
    rootenc_lds[64 + j]  = 1.0f;         // cos(0*w)
    rootenc_lds[128 + j] = cosf(wj);     // cos(1*w)
    // equality masks + freq (intra-wave LDS RAW on nid_lds: hw-ordered via lgkmcnt)
    const int my = nid_lds[j];
    unsigned long long m = 0ull;
    for (int k = 0; k < B; ++k)
      m |= ((unsigned long long)(nid_lds[k] == my)) << k;
    mask_lds[j] = m;
    freq_lds[j] = (float)__popcll(m) * 0.015625f;
  }
  __syncthreads();

  // ---------------- P1: node_enc -> encA (ring); time_enc -> encB; h_root ----------------
  enc_gemm_ring(nf_stage, Wn, bn, encA, b2, cg);
  {
    const float rts = root_ts[n];
#pragma unroll
    for (int q = 0; q < 8; ++q) {
      const int idx = q * 512 + t;       // stride-1 across lanes: conflict-free
      const int bb = idx >> 6, dd = idx & 63;
      encB[idx] = cosf((rts - ts_lds[bb]) * w_lds[dd]);
    }
  }
  {
    const int h = t >> 1, hf = t & 1;
    float a = 0.0f;
    for (int d = hf * 96; d < hf * 96 + 96; ++d)
      a = fmaf(rootenc_lds[d], Wr[d * HDIM + h], a);
    a += __shfl_xor(a, 1);
    if (hf == 0) hroot_lds[h] = fmaxf(a, 0.0f);
  }
  __syncthreads();

  // ---------------- P2: issue ef stage; accum node (d 0..63) ----------------
  stage_async(ef + (size_t)n * B * DF, nf_stage, t);
  float2 acc[16];
#pragma unroll
  for (int i = 0; i < 16; ++i) acc[i] = make_float2(0.f, 0.f);
  accum16(acc, encA, r16, Wl2 + c2);
  __syncthreads();

  // ---------------- P3: edge_enc -> encA (lite: acc[16] live, keep pressure low) ----------------
  enc_gemm_lite(nf_stage, We, be, encA, b2, cg);
  __syncthreads();

  // ---------------- P4: freq_enc -> nf_stage (free after P3); accum edge (d 64..127) ----------------
#pragma unroll
  for (int q = 0; q < 8; ++q) {
    const int idx = q * 512 + t;
    const int bb = idx >> 6, dd = idx & 63;
    nf_stage[idx] = cosf(freq_lds[bb] * w_lds[dd]);
  }
  accum16(acc, encA, r16, Wl2 + 64 * 128 + c2);
  __syncthreads();

  // ---------------- P6: accum time (128..191), freq (192..255), iden sparse (256..319) ----------------
  accum16(acc, encB, r16, Wl2 + 128 * 128 + c2);
  accum16(acc, nf_stage, r16, Wl2 + 192 * 128 + c2);
  {
    // iden[r][d] = (nid[d]==nid[r]); fmaf(0,w,acc)==acc exactly, so only set bits
    // contribute; ascending-d ctz iteration keeps bit-identical accumulation order.
    // FULLY unrolled so acc[i] index is compile-time (rule #20).
    const float2* Wlp = Wl2 + 256 * 128 + c2;
#pragma unroll
    for (int i = 0; i < 16; ++i) {
      unsigned long long m = mask_lds[r16 + i];   // wave-uniform -> no divergence
      while (m) {
        const int d = __builtin_ctzll(m);
        m &= m - 1;
        const float2 wv = Wlp[d * 128];
        acc[i].x += wv.x;  // == fmaf(1.0f, wv.x, acc)
        acc[i].y += wv.y;
      }
    }
  }

  // ---------------- scores: relu(h_link) . h_root; butterfly 64 + 2 LDS partials ----------------
  {
    const float2 hr = ((const float2*)hroot_lds)[c2];
#pragma unroll
    for (int i = 0; i < 16; ++i) {
      float s = fmaxf(acc[i].x, 0.f) * hr.x;
      s = fmaf(fmaxf(acc[i].y, 0.f), hr.y, s);
#pragma unroll
      for (int mm = 32; mm >= 1; mm >>= 1) s += __shfl_xor(s, mm);
      if ((t & 63) == 0) scpart[t >> 7][i][(t >> 6) & 1] = s;
    }
  }
  __syncthreads();

  // ---------------- P7: softmax + gumbel + top-16 (wave 0) ----------------
  if (t < B) {
    float s = (scpart[t >> 4][t & 15][0] + scpart[t >> 4][t & 15][1]) * 0.0625f;
    float m = s;
#pragma unroll
    for (int mm = 32; mm >= 1; mm >>= 1) m = fmaxf(m, __shfl_xor(m, mm));
    float e = expf(s - m);
    float sum = e;
#pragma unroll
    for (int mm = 32; mm >= 1; mm >>= 1) sum += __shfl_xor(sum, mm);
    float p = e / sum;
    out_probs[(size_t)n * B + t] = p;

    // partitionable threefry: block input (0, i), draw = out0 ^ out1
    uint32_t i = (uint32_t)(n * B + t);
    uint32_t x0 = 0u, x1 = i;
    threefry2x32(0u, 42u, x0, x1);
    uint32_t bits = x0 ^ x1;
    float f = __uint_as_float((bits >> 9) | 0x3f800000u) - 1.0f;
    const float TINY = 1.1754943508222875e-38f;
    float u = fmaxf(f * (1.0f - TINY) + TINY, TINY);
    float g = -logf(-logf(u));
    float keyv = logf(p + 1e-20f) + g;

    float v = keyv;
    for (int k = 0; k < KSAMP; ++k) {
      float bv = v; int bi = t;
#pragma unroll
      for (int mm = 32; mm >= 1; mm >>= 1) {
        float ov = __shfl_xor(bv, mm);
        int   oi = __shfl_xor(bi, mm);
        if (ov > bv || (ov == bv && oi < bi)) { bv = ov; bi = oi; }
      }
      if (t == 0) out_action[(size_t)n * KSAMP + k] = (float)bi;
      if (t == bi) v = -3.402823466e+38f;
    }
  }
}

extern "C" void kernel_launch(void* const* d_in, const int* in_sizes, int n_in,
                              void* d_out, int out_size, void* d_ws, size_t ws_size,
                              hipStream_t stream) {
  const float* rootf = (const float*)d_in[0];
  const float* rts   = (const float*)d_in[1];
  const float* nf    = (const float*)d_in[2];
  const float* ef    = (const float*)d_in[3];
  const float* nts   = (const float*)d_in[4];
  const int*   nid   = (const int*)d_in[5];
  const float* Wn    = (const float*)d_in[6];
  const float* bn    = (const float*)d_in[7];
  const float* We    = (const float*)d_in[8];
  const float* be    = (const float*)d_in[9];
  const float* Wl    = (const float*)d_in[10];
  const float* Wr    = (const float*)d_in[11];

  const int n = in_sizes[1];                   // 4096 rows
  float* probs  = (float*)d_out;               // [n,64] f32
  float* action = probs + (size_t)n * B;       // [n,16] written as f32 values

  AdaptSampler_kernel<<<dim3(n), dim3(THREADS), 0, stream>>>(
      rootf, rts, nf, ef, nts, nid, Wn, bn, We, be, Wl, Wr, probs, action);
}